// Round 4
// baseline (99.027 us; speedup 1.0000x reference)
//
#include <hip/hip_runtime.h>

#define NN  10000
#define G   10          // i's per block; G | 100 so a block's i's share a row
#define BLK 256

#if __has_builtin(__builtin_amdgcn_sqrtf)
#define FSQRT(x) __builtin_amdgcn_sqrtf(x)   // raw v_sqrt_f32, +-1 ulp
#else
#define FSQRT(x) sqrtf(x)
#endif

// ---------- kernel A: build T table (blocks 0..99) + compact active list (block 100)
// T[u*100+c] = sum_b sqrt(u^2 + (c-b)^2), u,c in [0,100)
__global__ __launch_bounds__(BLK) void HausdorffDistance_prep(
    const float* __restrict__ gt, float* __restrict__ T,
    float2* __restrict__ list, int* __restrict__ cnt)
{
    const int tid = threadIdx.x;
    const int u = blockIdx.x;
    if (u < 100) {
        if (tid < 100) {
            const float u2 = (float)(u * u);
            const float c  = (float)tid;
            float s = 0.0f;
#pragma unroll 4
            for (int b = 0; b < 100; ++b) {
                float t = c - (float)b;
                s += FSQRT(fmaf(t, t, u2));
            }
            T[u * 100 + tid] = s;
        }
    } else {
        // single compaction block: gather (row, col) of gt >= 0.5 as floats
        __shared__ int lcnt;
        if (tid == 0) lcnt = 0;
        __syncthreads();
        for (int j = tid; j < NN; j += BLK) {
            if (gt[j] >= 0.5f) {
                int p = atomicAdd(&lcnt, 1);
                float af = (float)(j / 100);
                float bf = (float)(j % 100);
                list[p] = make_float2(af, bf);
            }
        }
        __syncthreads();
        if (tid == 0) *cnt = lcnt;
    }
}

// ---------- kernel B: S1[i] = sum_a T[|ri-a|, ci]  (full row-sum of D)
__global__ __launch_bounds__(BLK) void HausdorffDistance_s1(
    const float* __restrict__ T, float* __restrict__ S1)
{
    const int i = blockIdx.x * BLK + threadIdx.x;
    if (i >= NN) return;
    const int ri = i / 100, ci = i % 100;
    float s = 0.0f;
#pragma unroll 4
    for (int a = 0; a < 100; ++a) {
        int u = ri - a; u = (u < 0) ? -u : u;
        s += T[u * 100 + ci];
    }
    S1[i] = s;
}

// ---------- kernel C: A_i = sum over active list of dist; loss = |px*S1 - A| / N^2
__global__ __launch_bounds__(BLK) void HausdorffDistance_28406913696124_kernel(
    const float* __restrict__ prob, const float* __restrict__ S1,
    const float2* __restrict__ list, const int* __restrict__ cnt,
    float* __restrict__ out)
{
    __shared__ float sA[G];
    const int tid = threadIdx.x;
    if (tid < G) sA[tid] = 0.0f;
    __syncthreads();

    const int n = *cnt;
    const int i0 = blockIdx.x * G;               // G | 100 -> shared row
    const float ri = (float)(i0 / 100);
    const float c0 = (float)(i0 % 100);

    float acc[G];
#pragma unroll
    for (int g = 0; g < G; ++g) acc[g] = 0.0f;

    for (int m = tid; m < n; m += BLK) {
        float2 ab = list[m];                     // coalesced dwordx2, L2-hit
        float dxa = ri - ab.x;
        float dx2 = dxa * dxa;                   // shared across G cols
        float dyb = c0 - ab.y;
#pragma unroll
        for (int g = 0; g < G; ++g) {
            float dy = dyb + (float)g;           // inline-const add
            acc[g] += FSQRT(fmaf(dy, dy, dx2));  // 4 insts per pair total
        }
    }

    // 64-lane butterfly reduction, then cross-wave via LDS atomics
#pragma unroll
    for (int g = 0; g < G; ++g) {
#pragma unroll
        for (int off = 32; off >= 1; off >>= 1)
            acc[g] += __shfl_xor(acc[g], off, 64);
    }
    if ((tid & 63) == 0) {
#pragma unroll
        for (int g = 0; g < G; ++g) atomicAdd(&sA[g], acc[g]);
    }
    __syncthreads();

    if (tid == 0) {
        float t = 0.0f;
#pragma unroll
        for (int g = 0; g < G; ++g) {
            float px = (prob[i0 + g] >= 0.5f) ? 1.0f : 0.0f;
            t += fabsf(px * S1[i0 + g] - sA[g]);   // loss_i * N
        }
        atomicAdd(out, t * 1.0e-8f);               // / N^2
    }
}

extern "C" void kernel_launch(void* const* d_in, const int* in_sizes, int n_in,
                              void* d_out, int out_size, void* d_ws, size_t ws_size,
                              hipStream_t stream) {
    const float* prob = (const float*)d_in[0];   // prob_map [1,100,100] fp32
    const float* gt   = (const float*)d_in[1];   // gt_map   [1,100,100] fp32
    float* out = (float*)d_out;                  // scalar fp32

    // workspace layout (ws poisoned 0xAA each call; everything rewritten below)
    char* ws = (char*)d_ws;
    float*  T    = (float*)ws;                   // 10000 f32  @ 0
    float*  S1   = (float*)(ws + 40000);         // 10000 f32  @ 40000
    int*    cnt  = (int*)(ws + 80000);           // 1 int      @ 80000
    float2* list = (float2*)(ws + 80016);        // <=10000 float2 @ 80016 (16B-aligned)

    (void)hipMemsetAsync(out, 0, sizeof(float), stream);

    HausdorffDistance_prep<<<101, BLK, 0, stream>>>(gt, T, list, cnt);
    HausdorffDistance_s1<<<(NN + BLK - 1) / BLK, BLK, 0, stream>>>(T, S1);
    HausdorffDistance_28406913696124_kernel<<<NN / G, BLK, 0, stream>>>(
        prob, S1, list, cnt, out);
}

// Round 5
// 98.184 us; speedup vs baseline: 1.0086x; 1.0086x over previous
//
#include <hip/hip_runtime.h>

#define NN  10000
#define G   10          // i's per block in kernel C; G | 100 -> shared row
#define BLKC 512        // kernel C block: 8 waves, ~4 blocks/CU = full occupancy
#define BLKP 256

#if __has_builtin(__builtin_amdgcn_sqrtf)
#define FSQRT(x) __builtin_amdgcn_sqrtf(x)   // raw v_sqrt_f32, +-1 ulp
#else
#define FSQRT(x) sqrtf(x)
#endif

// ---------- kernel A: build T table (blocks 0..99) + compact active list (block 100)
// T[u*100+c] = sum_b sqrt(u^2 + (c-b)^2), u,c in [0,100)
__global__ __launch_bounds__(BLKP) void HausdorffDistance_prep(
    const float* __restrict__ gt, float* __restrict__ T,
    float2* __restrict__ list, int* __restrict__ cnt)
{
    const int tid = threadIdx.x;
    const int u = blockIdx.x;
    if (u < 100) {
        if (tid < 100) {
            const float u2 = (float)(u * u);
            const float c  = (float)tid;
            float s = 0.0f;
#pragma unroll 4
            for (int b = 0; b < 100; ++b) {
                float t = c - (float)b;
                s += FSQRT(fmaf(t, t, u2));
            }
            T[u * 100 + tid] = s;
        }
    } else {
        // compaction: wave-aggregated (1 atomic per wave per iteration)
        __shared__ int lcnt;
        if (tid == 0) lcnt = 0;
        __syncthreads();
        const int lane = tid & 63;
        for (int j = tid; j < NN; j += BLKP) {
            // lanes with smaller tid exit the loop LAST -> lane 0 present
            // whenever any lane of this wave is present
            bool act = (gt[j] >= 0.5f);
            unsigned long long m = __ballot(act);
            int nw = __popcll(m);
            int base = 0;
            if (lane == 0 && nw) base = atomicAdd(&lcnt, nw);
            base = __shfl(base, 0, 64);
            if (act) {
                int prefix = __popcll(m & ((1ull << lane) - 1ull));
                float jf = (float)j;
                float af = floorf(fmaf(jf, 0.01f, 5.0e-4f));  // row, exact
                float bf = fmaf(af, -100.0f, jf);             // col, exact
                list[base + prefix] = make_float2(af, bf);
            }
        }
        __syncthreads();
        if (tid == 0) *cnt = lcnt;
    }
}

// ---------- kernel B: S1[r*100+c] = sum_a T[|r-a|, c]  (full row-sum of D)
// one block per output row r; threads 0..99 handle column c
__global__ __launch_bounds__(128) void HausdorffDistance_s1(
    const float* __restrict__ T, float* __restrict__ S1)
{
    const int c = threadIdx.x;
    const int r = blockIdx.x;
    if (c >= 100) return;
    float s = 0.0f;
#pragma unroll 4
    for (int a = 0; a < 100; ++a) {
        int u = r - a; u = (u < 0) ? -u : u;
        s += T[u * 100 + c];          // coalesced across c
    }
    S1[r * 100 + c] = s;
}

// ---------- kernel C: A_i = sum over active list; loss = sum_i |px*S1 - A| / N^2
__global__ __launch_bounds__(BLKC) void HausdorffDistance_28406913696124_kernel(
    const float* __restrict__ prob, const float* __restrict__ S1,
    const float2* __restrict__ list, const int* __restrict__ cnt,
    float* __restrict__ out)
{
    __shared__ float sA[G];
    const int tid = threadIdx.x;
    if (tid < G) sA[tid] = 0.0f;
    __syncthreads();

    const int n = *cnt;
    const int i0 = blockIdx.x * G;               // G | 100 -> shared row
    const float ri = (float)(i0 / 100);
    const float c0 = (float)(i0 % 100);

    float acc[G];
#pragma unroll
    for (int g = 0; g < G; ++g) acc[g] = 0.0f;

    for (int m = tid; m < n; m += BLKC) {
        float2 ab = list[m];                     // coalesced dwordx2, L1/L2-hit
        float dxa = ri - ab.x;
        float dx2 = dxa * dxa;                   // shared across G cols
        float dyb = c0 - ab.y;
#pragma unroll
        for (int g = 0; g < G; ++g) {
            float dy = dyb + (float)g;           // inline-const add
            acc[g] += FSQRT(fmaf(dy, dy, dx2));  // 4 insts per pair
        }
    }

    // 64-lane butterfly reduction, then cross-wave via LDS atomics
#pragma unroll
    for (int g = 0; g < G; ++g) {
#pragma unroll
        for (int off = 32; off >= 1; off >>= 1)
            acc[g] += __shfl_xor(acc[g], off, 64);
    }
    if ((tid & 63) == 0) {                       // 8 waves -> 8 atomics per g
#pragma unroll
        for (int g = 0; g < G; ++g) atomicAdd(&sA[g], acc[g]);
    }
    __syncthreads();

    if (tid == 0) {
        float t = 0.0f;
#pragma unroll
        for (int g = 0; g < G; ++g) {
            float px = (prob[i0 + g] >= 0.5f) ? 1.0f : 0.0f;
            t += fabsf(px * S1[i0 + g] - sA[g]);   // loss_i * N
        }
        atomicAdd(out, t * 1.0e-8f);               // / N^2
    }
}

extern "C" void kernel_launch(void* const* d_in, const int* in_sizes, int n_in,
                              void* d_out, int out_size, void* d_ws, size_t ws_size,
                              hipStream_t stream) {
    const float* prob = (const float*)d_in[0];   // prob_map [1,100,100] fp32
    const float* gt   = (const float*)d_in[1];   // gt_map   [1,100,100] fp32
    float* out = (float*)d_out;                  // scalar fp32

    // workspace layout (ws poisoned 0xAA each call; everything rewritten below)
    char* ws = (char*)d_ws;
    float*  T    = (float*)ws;                   // 10000 f32  @ 0
    float*  S1   = (float*)(ws + 40000);         // 10000 f32  @ 40000
    int*    cnt  = (int*)(ws + 80000);           // 1 int      @ 80000
    float2* list = (float2*)(ws + 80016);        // <=10000 float2 @ 80016

    (void)hipMemsetAsync(out, 0, sizeof(float), stream);

    HausdorffDistance_prep<<<101, BLKP, 0, stream>>>(gt, T, list, cnt);
    HausdorffDistance_s1<<<100, 128, 0, stream>>>(T, S1);
    HausdorffDistance_28406913696124_kernel<<<NN / G, BLKC, 0, stream>>>(
        prob, S1, list, cnt, out);
}